// Round 3
// baseline (7542.260 us; speedup 1.0000x reference)
//
#include <hip/hip_runtime.h>
#include <hip/hip_bf16.h>

// Problem constants (fixed by the reference)
constexpr int NNODES = 200000;   // 4 graphs x 50000
constexpr int NGRAPH_NODES = 50000;
constexpr int NE = 3200000;
constexpr int H = 64;

// Bucketed scatter parameters
constexpr int BUCKET = 256;                       // nodes per bucket
constexpr int NB = (NNODES + BUCKET - 1) / BUCKET; // 782 buckets
constexpr int SRC_BITS = 18;                      // 200000 < 2^18
constexpr unsigned SRC_MASK = (1u << SRC_BITS) - 1;

// ---------------------------------------------------------------------------
// Fused 3-GEMM per inception block: Y = X@Wl + (Bl+B1+B2), S1 = X@W1, S2 = X@W2
// ---------------------------------------------------------------------------
template <int DI>
__global__ __launch_bounds__(256) void gemm3_kernel(
    const float* __restrict__ X,
    const float* __restrict__ Wl, const float* __restrict__ Bl,
    const float* __restrict__ W1, const float* __restrict__ B1,
    const float* __restrict__ W2, const float* __restrict__ B2,
    float* __restrict__ Y, float* __restrict__ S1, float* __restrict__ S2)
{
    __shared__ float xs[32][DI];
    const int tid = threadIdx.x;
    const int f = tid & 63;
    const int r = tid >> 6;
    const int base = blockIdx.x * 32;

    const float4* xg = reinterpret_cast<const float4*>(X + (size_t)base * DI);
    float4* xsv = reinterpret_cast<float4*>(&xs[0][0]);
    constexpr int NV = 32 * DI / 4;
    #pragma unroll
    for (int i = tid; i < NV; i += 256) xsv[i] = xg[i];
    __syncthreads();

    float accL[8], acc1[8], acc2[8];
    #pragma unroll
    for (int i = 0; i < 8; ++i) { accL[i] = 0.f; acc1[i] = 0.f; acc2[i] = 0.f; }

    for (int k = 0; k < DI; ++k) {
        float wl = Wl[k * H + f];
        float w1 = W1[k * H + f];
        float w2 = W2[k * H + f];
        #pragma unroll
        for (int i = 0; i < 8; ++i) {
            float xv = xs[r * 8 + i][k];
            accL[i] = fmaf(xv, wl, accL[i]);
            acc1[i] = fmaf(xv, w1, acc1[i]);
            acc2[i] = fmaf(xv, w2, acc2[i]);
        }
    }

    float bias = Bl[f] + B1[f] + B2[f];
    #pragma unroll
    for (int i = 0; i < 8; ++i) {
        size_t n = (size_t)(base + r * 8 + i);
        Y[n * H + f]  = accL[i] + bias;
        S1[n * H + f] = acc1[i];
        S2[n * H + f] = acc2[i];
    }
}

// ---------------------------------------------------------------------------
// Block 3 GEMM (DI=64 -> DO=1): three dot products per node.
// ---------------------------------------------------------------------------
__global__ __launch_bounds__(256) void gemm3_out1_kernel(
    const float* __restrict__ X,
    const float* __restrict__ Wl, const float* __restrict__ Bl,
    const float* __restrict__ W1, const float* __restrict__ B1,
    const float* __restrict__ W2, const float* __restrict__ B2,
    float* __restrict__ Y, float* __restrict__ S1, float* __restrict__ S2)
{
    __shared__ float wls[64], w1s[64], w2s[64];
    const int tid = threadIdx.x;
    if (tid < 64) { wls[tid] = Wl[tid]; w1s[tid] = W1[tid]; w2s[tid] = W2[tid]; }
    __syncthreads();
    const int n = blockIdx.x * 256 + tid;
    if (n >= NNODES) return;
    const float4* xr = reinterpret_cast<const float4*>(X + (size_t)n * H);
    float aL = 0.f, a1 = 0.f, a2 = 0.f;
    #pragma unroll
    for (int kv = 0; kv < 16; ++kv) {
        float4 xv = xr[kv];
        int k = kv * 4;
        aL = fmaf(xv.x, wls[k + 0], aL); a1 = fmaf(xv.x, w1s[k + 0], a1); a2 = fmaf(xv.x, w2s[k + 0], a2);
        aL = fmaf(xv.y, wls[k + 1], aL); a1 = fmaf(xv.y, w1s[k + 1], a1); a2 = fmaf(xv.y, w2s[k + 1], a2);
        aL = fmaf(xv.z, wls[k + 2], aL); a1 = fmaf(xv.z, w1s[k + 2], a1); a2 = fmaf(xv.z, w2s[k + 2], a2);
        aL = fmaf(xv.w, wls[k + 3], aL); a1 = fmaf(xv.w, w1s[k + 3], a1); a2 = fmaf(xv.w, w2s[k + 3], a2);
    }
    float bias = Bl[0] + B1[0] + B2[0];
    Y[n] = aL + bias; S1[n] = a1; S2[n] = a2;
}

// ---------------------------------------------------------------------------
// Counting sort of edges by dst bucket (dst >> 8). Three passes.
// ---------------------------------------------------------------------------
__global__ __launch_bounds__(256) void hist_kernel(
    const int* __restrict__ dst, int* __restrict__ gh)
{
    __shared__ int lh[NB];
    const int tid = threadIdx.x;
    for (int i = tid; i < NB; i += 256) lh[i] = 0;
    __syncthreads();
    const int t = blockIdx.x * 256 + tid;
    const int tot = gridDim.x * 256;
    for (int e = t; e < NE; e += tot) atomicAdd(&lh[dst[e] >> 8], 1);
    __syncthreads();
    for (int i = tid; i < NB; i += 256) {
        int c = lh[i];
        if (c) atomicAdd(&gh[i], c);
    }
}

__global__ __launch_bounds__(1024) void scan_kernel(
    const int* __restrict__ gh, int* __restrict__ base, int* __restrict__ cursor)
{
    __shared__ int tmp[1024];
    const int tid = threadIdx.x;
    int v = (tid < NB) ? gh[tid] : 0;
    tmp[tid] = v;
    __syncthreads();
    for (int off = 1; off < 1024; off <<= 1) {
        int t = (tid >= off) ? tmp[tid - off] : 0;
        __syncthreads();
        tmp[tid] += t;
        __syncthreads();
    }
    if (tid == 0) base[0] = 0;
    if (tid < NB) {
        base[tid + 1] = tmp[tid];
        cursor[tid] = tmp[tid] - v;   // exclusive prefix
    }
}

__global__ __launch_bounds__(256) void place_kernel(
    const int* __restrict__ EI, const float* __restrict__ EW,
    int* __restrict__ cursor, uint2* __restrict__ sorted)
{
    const int t = blockIdx.x * 256 + threadIdx.x;
    const int tot = gridDim.x * 256;
    for (int e = t; e < NE; e += tot) {
        unsigned s = (unsigned)EI[e];
        unsigned d = (unsigned)EI[NE + e];
        float w = EW[e];
        int b = d >> 8;
        int pos = atomicAdd(&cursor[b], 1);
        sorted[pos] = make_uint2(s | ((d & (BUCKET - 1)) << SRC_BITS),
                                 __float_as_uint(w));
    }
}

// ---------------------------------------------------------------------------
// Bucketed 64-dim aggregation for BOTH edge sets: one block per dst bucket.
// LDS accumulator [BUCKET][64] f32 (64 KB -> 2 blocks/CU). Wave per edge:
// coalesced 256B gather of S[src], ds_add_f32 into LDS (2-way alias, free).
// Exclusive bucket ownership -> plain += writeout, no global atomics.
// ---------------------------------------------------------------------------
__global__ __launch_bounds__(512) void scatter_accum64_kernel(
    const uint2* __restrict__ sorted1, const int* __restrict__ base1,
    const uint2* __restrict__ sorted2, const int* __restrict__ base2,
    const float* __restrict__ S1, const float* __restrict__ S2,
    float* __restrict__ Y)
{
    __shared__ float acc[BUCKET * 64];
    const int tid = threadIdx.x;
    const int lane = tid & 63;
    const int wave = tid >> 6;            // 0..7
    const int b = blockIdx.x;

    float4* av = reinterpret_cast<float4*>(acc);
    #pragma unroll
    for (int i = tid; i < BUCKET * 16; i += 512) av[i] = make_float4(0.f, 0.f, 0.f, 0.f);
    __syncthreads();

    const uint2* sArr[2] = {sorted1, sorted2};
    const int*   bArr[2] = {base1, base2};
    const float* SArr[2] = {S1, S2};

    #pragma unroll
    for (int set = 0; set < 2; ++set) {
        const uint2* sorted = sArr[set];
        const float* S = SArr[set];
        const int lo = bArr[set][b];
        const int hi = bArr[set][b + 1];
        int e = lo + wave;
        // 4-deep manual unroll for memory-level parallelism
        for (; e + 24 < hi; e += 32) {
            uint2 p0 = sorted[e];
            uint2 p1 = sorted[e + 8];
            uint2 p2 = sorted[e + 16];
            uint2 p3 = sorted[e + 24];
            float v0 = S[(size_t)(p0.x & SRC_MASK) * 64 + lane];
            float v1 = S[(size_t)(p1.x & SRC_MASK) * 64 + lane];
            float v2 = S[(size_t)(p2.x & SRC_MASK) * 64 + lane];
            float v3 = S[(size_t)(p3.x & SRC_MASK) * 64 + lane];
            atomicAdd(&acc[(p0.x >> SRC_BITS) * 64 + lane], __uint_as_float(p0.y) * v0);
            atomicAdd(&acc[(p1.x >> SRC_BITS) * 64 + lane], __uint_as_float(p1.y) * v1);
            atomicAdd(&acc[(p2.x >> SRC_BITS) * 64 + lane], __uint_as_float(p2.y) * v2);
            atomicAdd(&acc[(p3.x >> SRC_BITS) * 64 + lane], __uint_as_float(p3.y) * v3);
        }
        for (; e < hi; e += 8) {
            uint2 p = sorted[e];
            float v = S[(size_t)(p.x & SRC_MASK) * 64 + lane];
            atomicAdd(&acc[(p.x >> SRC_BITS) * 64 + lane], __uint_as_float(p.y) * v);
        }
    }
    __syncthreads();

    // Writeout: bucket exclusively owned -> plain read-modify-write
    for (int r = wave; r < BUCKET; r += 8) {
        int node = b * BUCKET + r;
        if (node < NNODES) {
            size_t idx = (size_t)node * 64 + lane;
            Y[idx] += acc[r * 64 + lane];
        }
    }
}

// ---------------------------------------------------------------------------
// Bucketed scalar aggregation (block 3), both edge sets.
// ---------------------------------------------------------------------------
__global__ __launch_bounds__(256) void scatter_accum1_kernel(
    const uint2* __restrict__ sorted1, const int* __restrict__ base1,
    const uint2* __restrict__ sorted2, const int* __restrict__ base2,
    const float* __restrict__ S1, const float* __restrict__ S2,
    float* __restrict__ Y)
{
    __shared__ float acc[BUCKET];
    const int tid = threadIdx.x;
    const int b = blockIdx.x;
    acc[tid] = 0.f;
    __syncthreads();

    const uint2* sArr[2] = {sorted1, sorted2};
    const int*   bArr[2] = {base1, base2};
    const float* SArr[2] = {S1, S2};

    #pragma unroll
    for (int set = 0; set < 2; ++set) {
        const uint2* sorted = sArr[set];
        const float* S = SArr[set];
        const int lo = bArr[set][b];
        const int hi = bArr[set][b + 1];
        for (int e = lo + tid; e < hi; e += 256) {
            uint2 p = sorted[e];
            atomicAdd(&acc[p.x >> SRC_BITS],
                      __uint_as_float(p.y) * S[p.x & SRC_MASK]);
        }
    }
    __syncthreads();

    int node = b * BUCKET + tid;
    if (node < NNODES) Y[node] += acc[tid];
}

// ---------------------------------------------------------------------------
// Fallback (atomic) scatters — used only if ws_size is too small for sorting.
// ---------------------------------------------------------------------------
__global__ __launch_bounds__(256) void scatter64_kernel(
    const int* __restrict__ EI, const float* __restrict__ EW,
    const float* __restrict__ S, float* __restrict__ Y)
{
    const int lane = threadIdx.x & 63;
    const int wid = (blockIdx.x * 256 + threadIdx.x) >> 6;
    const int nw = (gridDim.x * 256) >> 6;
    for (int e = wid; e < NE; e += nw) {
        int s = EI[e];
        int d = EI[NE + e];
        float w = EW[e];
        float v = S[(size_t)s * H + lane];
        unsafeAtomicAdd(&Y[(size_t)d * H + lane], w * v);
    }
}

__global__ __launch_bounds__(256) void scatter1_kernel(
    const int* __restrict__ EI, const float* __restrict__ EW,
    const float* __restrict__ S, float* __restrict__ Y)
{
    const int t = blockIdx.x * 256 + threadIdx.x;
    const int tot = gridDim.x * 256;
    for (int e = t; e < NE; e += tot) {
        int s = EI[e];
        int d = EI[NE + e];
        float w = EW[e];
        unsafeAtomicAdd(&Y[d], w * S[s]);
    }
}

// ---------------------------------------------------------------------------
// Readout
// ---------------------------------------------------------------------------
__device__ __forceinline__ unsigned fkey(float v) {
    unsigned u = __float_as_uint(v);
    return (u & 0x80000000u) ? ~u : (u | 0x80000000u);
}

__global__ __launch_bounds__(256) void readout_kernel(
    const float* __restrict__ Y3, float* __restrict__ body1,
    float* __restrict__ body2, unsigned int* __restrict__ keys)
{
    __shared__ unsigned int smax[4];
    const int tid = threadIdx.x;
    if (tid < 4) smax[tid] = 0u;
    __syncthreads();
    const int i = blockIdx.x * 256 + tid;
    if (i < NNODES) {
        float v = Y3[i];
        body1[i] = v;
        body2[i] = v;
        atomicMax(&smax[i / NGRAPH_NODES], fkey(v));
    }
    __syncthreads();
    if (tid < 4 && smax[tid]) atomicMax(&keys[tid], smax[tid]);
}

__global__ void finalize_kernel(const unsigned int* __restrict__ keys,
                                float* __restrict__ out)
{
    int i = threadIdx.x;
    if (i < 4) {
        unsigned k = keys[i];
        unsigned u = (k & 0x80000000u) ? (k ^ 0x80000000u) : ~k;
        out[i] = __uint_as_float(u);
    }
}

// ---------------------------------------------------------------------------
extern "C" void kernel_launch(void* const* d_in, const int* in_sizes, int n_in,
                              void* d_out, int out_size, void* d_ws, size_t ws_size,
                              hipStream_t stream)
{
    const float* x   = (const float*)d_in[0];
    const int*   ei  = (const int*)d_in[1];
    const float* ew  = (const float*)d_in[2];
    const int*   ei2 = (const int*)d_in[3];
    const float* ew2 = (const float*)d_in[4];
    const float* W[18];
    for (int i = 0; i < 18; ++i) W[i] = (const float*)d_in[6 + i];

    float* Y  = (float*)d_ws;                       // 200000 x 64
    float* S1 = Y + (size_t)NNODES * H;
    float* S2 = S1 + (size_t)NNODES * H;
    float* Y3 = S2 + (size_t)NNODES * H;            // 200000
    uint2* sorted1 = (uint2*)(Y3 + NNODES);         // NE uint2
    uint2* sorted2 = sorted1 + NE;
    unsigned int* keys = (unsigned int*)(sorted2 + NE);
    int* gh1   = (int*)(keys + 4);
    int* gh2   = gh1 + NB;
    int* base1 = gh2 + NB;          // NB+1
    int* base2 = base1 + NB + 1;    // NB+1
    int* cur1  = base2 + NB + 1;    // NB
    int* cur2  = cur1 + NB;         // NB
    size_t needed = (size_t)((char*)(cur2 + NB) - (char*)d_ws);

    float* out = (float*)d_out;   // [0..3]=graph max, then x twice

    const bool sorted_path = (ws_size >= needed);

    if (sorted_path) {
        // zero keys + histograms in one shot
        hipMemsetAsync(keys, 0, (4 + 2 * NB) * sizeof(int), stream);

        // Build dst-sorted edge lists (reused by all 3 inception blocks)
        hist_kernel<<<1024, 256, 0, stream>>>(ei + NE,  gh1);
        hist_kernel<<<1024, 256, 0, stream>>>(ei2 + NE, gh2);
        scan_kernel<<<1, 1024, 0, stream>>>(gh1, base1, cur1);
        scan_kernel<<<1, 1024, 0, stream>>>(gh2, base2, cur2);
        place_kernel<<<2048, 256, 0, stream>>>(ei,  ew,  cur1, sorted1);
        place_kernel<<<2048, 256, 0, stream>>>(ei2, ew2, cur2, sorted2);

        // Block 1
        gemm3_kernel<128><<<NNODES / 32, 256, 0, stream>>>(
            x, W[0], W[1], W[2], W[3], W[4], W[5], Y, S1, S2);
        scatter_accum64_kernel<<<NB, 512, 0, stream>>>(
            sorted1, base1, sorted2, base2, S1, S2, Y);

        // Block 2 (in-place on Y)
        gemm3_kernel<64><<<NNODES / 32, 256, 0, stream>>>(
            Y, W[6], W[7], W[8], W[9], W[10], W[11], Y, S1, S2);
        scatter_accum64_kernel<<<NB, 512, 0, stream>>>(
            sorted1, base1, sorted2, base2, S1, S2, Y);

        // Block 3 (S1/S2 reused as [NNODES] scalars)
        gemm3_out1_kernel<<<(NNODES + 255) / 256, 256, 0, stream>>>(
            Y, W[12], W[13], W[14], W[15], W[16], W[17], Y3, S1, S2);
        scatter_accum1_kernel<<<NB, 256, 0, stream>>>(
            sorted1, base1, sorted2, base2, S1, S2, Y3);
    } else {
        unsigned int* okeys = (unsigned int*)(Y3 + NNODES);
        keys = okeys;
        hipMemsetAsync(keys, 0, 4 * sizeof(unsigned int), stream);

        gemm3_kernel<128><<<NNODES / 32, 256, 0, stream>>>(
            x, W[0], W[1], W[2], W[3], W[4], W[5], Y, S1, S2);
        scatter64_kernel<<<2048, 256, 0, stream>>>(ei,  ew,  S1, Y);
        scatter64_kernel<<<2048, 256, 0, stream>>>(ei2, ew2, S2, Y);

        gemm3_kernel<64><<<NNODES / 32, 256, 0, stream>>>(
            Y, W[6], W[7], W[8], W[9], W[10], W[11], Y, S1, S2);
        scatter64_kernel<<<2048, 256, 0, stream>>>(ei,  ew,  S1, Y);
        scatter64_kernel<<<2048, 256, 0, stream>>>(ei2, ew2, S2, Y);

        gemm3_out1_kernel<<<(NNODES + 255) / 256, 256, 0, stream>>>(
            Y, W[12], W[13], W[14], W[15], W[16], W[17], Y3, S1, S2);
        scatter1_kernel<<<2048, 256, 0, stream>>>(ei,  ew,  S1, Y3);
        scatter1_kernel<<<2048, 256, 0, stream>>>(ei2, ew2, S2, Y3);
    }

    readout_kernel<<<(NNODES + 255) / 256, 256, 0, stream>>>(
        Y3, out + 4, out + 4 + NNODES, keys);
    finalize_kernel<<<1, 64, 0, stream>>>(keys, out);
}

// Round 4
// 2817.010 us; speedup vs baseline: 2.6774x; 2.6774x over previous
//
#include <hip/hip_runtime.h>
#include <hip/hip_bf16.h>

// Problem constants (fixed by the reference)
constexpr int NNODES = 200000;   // 4 graphs x 50000
constexpr int NGRAPH_NODES = 50000;
constexpr int NE = 3200000;
constexpr int H = 64;
constexpr int CPT = 196;         // scan chunk: 1024*196 >= 200000

// ---------------------------------------------------------------------------
// Fused 3-GEMM per inception block: Y = X@Wl + (Bl+B1+B2), S1 = X@W1, S2 = X@W2
// ---------------------------------------------------------------------------
template <int DI>
__global__ __launch_bounds__(256) void gemm3_kernel(
    const float* __restrict__ X,
    const float* __restrict__ Wl, const float* __restrict__ Bl,
    const float* __restrict__ W1, const float* __restrict__ B1,
    const float* __restrict__ W2, const float* __restrict__ B2,
    float* __restrict__ Y, float* __restrict__ S1, float* __restrict__ S2)
{
    __shared__ float xs[32][DI];
    const int tid = threadIdx.x;
    const int f = tid & 63;
    const int r = tid >> 6;
    const int base = blockIdx.x * 32;

    const float4* xg = reinterpret_cast<const float4*>(X + (size_t)base * DI);
    float4* xsv = reinterpret_cast<float4*>(&xs[0][0]);
    constexpr int NV = 32 * DI / 4;
    #pragma unroll
    for (int i = tid; i < NV; i += 256) xsv[i] = xg[i];
    __syncthreads();

    float accL[8], acc1[8], acc2[8];
    #pragma unroll
    for (int i = 0; i < 8; ++i) { accL[i] = 0.f; acc1[i] = 0.f; acc2[i] = 0.f; }

    for (int k = 0; k < DI; ++k) {
        float wl = Wl[k * H + f];
        float w1 = W1[k * H + f];
        float w2 = W2[k * H + f];
        #pragma unroll
        for (int i = 0; i < 8; ++i) {
            float xv = xs[r * 8 + i][k];
            accL[i] = fmaf(xv, wl, accL[i]);
            acc1[i] = fmaf(xv, w1, acc1[i]);
            acc2[i] = fmaf(xv, w2, acc2[i]);
        }
    }

    float bias = Bl[f] + B1[f] + B2[f];
    #pragma unroll
    for (int i = 0; i < 8; ++i) {
        size_t n = (size_t)(base + r * 8 + i);
        Y[n * H + f]  = accL[i] + bias;
        S1[n * H + f] = acc1[i];
        S2[n * H + f] = acc2[i];
    }
}

// ---------------------------------------------------------------------------
// Block 3 GEMM (DI=64 -> DO=1): three dot products per node.
// ---------------------------------------------------------------------------
__global__ __launch_bounds__(256) void gemm3_out1_kernel(
    const float* __restrict__ X,
    const float* __restrict__ Wl, const float* __restrict__ Bl,
    const float* __restrict__ W1, const float* __restrict__ B1,
    const float* __restrict__ W2, const float* __restrict__ B2,
    float* __restrict__ Y, float* __restrict__ S1, float* __restrict__ S2)
{
    __shared__ float wls[64], w1s[64], w2s[64];
    const int tid = threadIdx.x;
    if (tid < 64) { wls[tid] = Wl[tid]; w1s[tid] = W1[tid]; w2s[tid] = W2[tid]; }
    __syncthreads();
    const int n = blockIdx.x * 256 + tid;
    if (n >= NNODES) return;
    const float4* xr = reinterpret_cast<const float4*>(X + (size_t)n * H);
    float aL = 0.f, a1 = 0.f, a2 = 0.f;
    #pragma unroll
    for (int kv = 0; kv < 16; ++kv) {
        float4 xv = xr[kv];
        int k = kv * 4;
        aL = fmaf(xv.x, wls[k + 0], aL); a1 = fmaf(xv.x, w1s[k + 0], a1); a2 = fmaf(xv.x, w2s[k + 0], a2);
        aL = fmaf(xv.y, wls[k + 1], aL); a1 = fmaf(xv.y, w1s[k + 1], a1); a2 = fmaf(xv.y, w2s[k + 1], a2);
        aL = fmaf(xv.z, wls[k + 2], aL); a1 = fmaf(xv.z, w1s[k + 2], a1); a2 = fmaf(xv.z, w2s[k + 2], a2);
        aL = fmaf(xv.w, wls[k + 3], aL); a1 = fmaf(xv.w, w1s[k + 3], a1); a2 = fmaf(xv.w, w2s[k + 3], a2);
    }
    float bias = Bl[0] + B1[0] + B2[0];
    Y[n] = aL + bias; S1[n] = a1; S2[n] = a2;
}

// ---------------------------------------------------------------------------
// Full counting sort by dst -> CSR (row_ptr + (src,w) pairs).
// ---------------------------------------------------------------------------
__global__ __launch_bounds__(256) void hist_full_kernel(
    const int* __restrict__ dst, int* __restrict__ cnt)
{
    const int t = blockIdx.x * 256 + threadIdx.x;
    const int tot = gridDim.x * 256;
    for (int e = t; e < NE; e += tot) atomicAdd(&cnt[dst[e]], 1);
}

__global__ __launch_bounds__(1024) void scan200k_kernel(
    const int* __restrict__ cnt, int* __restrict__ row_ptr, int* __restrict__ cursor)
{
    __shared__ int part[1024];
    const int t = threadIdx.x;
    const int lo = t * CPT;
    const int hi = min(lo + CPT, NNODES);
    int s = 0;
    for (int i = lo; i < hi; ++i) s += cnt[i];
    part[t] = s;
    __syncthreads();
    for (int off = 1; off < 1024; off <<= 1) {
        int v = (t >= off) ? part[t - off] : 0;
        __syncthreads();
        part[t] += v;
        __syncthreads();
    }
    int run = (t == 0) ? 0 : part[t - 1];   // exclusive prefix of this chunk
    for (int i = lo; i < hi; ++i) {
        int c = cnt[i];
        row_ptr[i] = run;
        cursor[i] = run;
        run += c;
    }
    if (t == 1023) row_ptr[NNODES] = part[1023];
}

__global__ __launch_bounds__(256) void place_kernel(
    const int* __restrict__ EI, const float* __restrict__ EW,
    int* __restrict__ cursor, uint2* __restrict__ sorted)
{
    const int t = blockIdx.x * 256 + threadIdx.x;
    const int tot = gridDim.x * 256;
    for (int e = t; e < NE; e += tot) {
        int s = EI[e];
        int d = EI[NE + e];
        int pos = atomicAdd(&cursor[d], 1);
        sorted[pos] = make_uint2((unsigned)s, __float_as_uint(EW[e]));
    }
}

// ---------------------------------------------------------------------------
// CSR SpMV aggregation, 64 features: one wave per dst row, 8 rows/wave.
// No atomics: wave exclusively owns its rows. Both edge sets in one pass.
// ---------------------------------------------------------------------------
__global__ __launch_bounds__(256) void csr_accum64_kernel(
    const uint2* __restrict__ E1, const int* __restrict__ rp1,
    const uint2* __restrict__ E2, const int* __restrict__ rp2,
    const float* __restrict__ S1, const float* __restrict__ S2,
    float* __restrict__ Y)
{
    const int lane = threadIdx.x & 63;
    const int wid = (blockIdx.x * 256 + threadIdx.x) >> 6;
    const int r0 = wid * 8;   // 25000 waves x 8 rows = 200000

    for (int r = r0; r < r0 + 8; ++r) {
        float acc = 0.f;
        {
            const int lo = rp1[r], hi = rp1[r + 1];
            int e = lo;
            for (; e + 4 <= hi; e += 4) {
                uint2 p0 = E1[e], p1 = E1[e + 1], p2 = E1[e + 2], p3 = E1[e + 3];
                float v0 = S1[(size_t)p0.x * H + lane];
                float v1 = S1[(size_t)p1.x * H + lane];
                float v2 = S1[(size_t)p2.x * H + lane];
                float v3 = S1[(size_t)p3.x * H + lane];
                acc = fmaf(__uint_as_float(p0.y), v0, acc);
                acc = fmaf(__uint_as_float(p1.y), v1, acc);
                acc = fmaf(__uint_as_float(p2.y), v2, acc);
                acc = fmaf(__uint_as_float(p3.y), v3, acc);
            }
            for (; e < hi; ++e) {
                uint2 p = E1[e];
                acc = fmaf(__uint_as_float(p.y), S1[(size_t)p.x * H + lane], acc);
            }
        }
        {
            const int lo = rp2[r], hi = rp2[r + 1];
            int e = lo;
            for (; e + 4 <= hi; e += 4) {
                uint2 p0 = E2[e], p1 = E2[e + 1], p2 = E2[e + 2], p3 = E2[e + 3];
                float v0 = S2[(size_t)p0.x * H + lane];
                float v1 = S2[(size_t)p1.x * H + lane];
                float v2 = S2[(size_t)p2.x * H + lane];
                float v3 = S2[(size_t)p3.x * H + lane];
                acc = fmaf(__uint_as_float(p0.y), v0, acc);
                acc = fmaf(__uint_as_float(p1.y), v1, acc);
                acc = fmaf(__uint_as_float(p2.y), v2, acc);
                acc = fmaf(__uint_as_float(p3.y), v3, acc);
            }
            for (; e < hi; ++e) {
                uint2 p = E2[e];
                acc = fmaf(__uint_as_float(p.y), S2[(size_t)p.x * H + lane], acc);
            }
        }
        Y[(size_t)r * H + lane] += acc;
    }
}

// ---------------------------------------------------------------------------
// Block-3 CSR aggregation (scalar) + fused readout.
// Thread per row; s1/s2 are 800 KB -> L2-resident gathers.
// ---------------------------------------------------------------------------
__device__ __forceinline__ unsigned fkey(float v) {
    unsigned u = __float_as_uint(v);
    return (u & 0x80000000u) ? ~u : (u | 0x80000000u);
}

__global__ __launch_bounds__(256) void csr_accum1_readout_kernel(
    const uint2* __restrict__ E1, const int* __restrict__ rp1,
    const uint2* __restrict__ E2, const int* __restrict__ rp2,
    const float* __restrict__ s1, const float* __restrict__ s2,
    const float* __restrict__ Y3,
    float* __restrict__ body1, float* __restrict__ body2,
    unsigned int* __restrict__ keys)
{
    __shared__ unsigned int smax[4];
    const int tid = threadIdx.x;
    if (tid < 4) smax[tid] = 0u;
    __syncthreads();
    const int r = blockIdx.x * 256 + tid;
    if (r < NNODES) {
        float acc = Y3[r];
        for (int e = rp1[r]; e < rp1[r + 1]; ++e) {
            uint2 p = E1[e];
            acc = fmaf(__uint_as_float(p.y), s1[p.x], acc);
        }
        for (int e = rp2[r]; e < rp2[r + 1]; ++e) {
            uint2 p = E2[e];
            acc = fmaf(__uint_as_float(p.y), s2[p.x], acc);
        }
        body1[r] = acc;
        body2[r] = acc;
        atomicMax(&smax[r / NGRAPH_NODES], fkey(acc));
    }
    __syncthreads();
    if (tid < 4 && smax[tid]) atomicMax(&keys[tid], smax[tid]);
}

__global__ void finalize_kernel(const unsigned int* __restrict__ keys,
                                float* __restrict__ out)
{
    int i = threadIdx.x;
    if (i < 4) {
        unsigned k = keys[i];
        unsigned u = (k & 0x80000000u) ? (k ^ 0x80000000u) : ~k;
        out[i] = __uint_as_float(u);
    }
}

// ---------------------------------------------------------------------------
// Fallback (atomic) scatters — used only if ws_size is too small.
// ---------------------------------------------------------------------------
__global__ __launch_bounds__(256) void scatter64_kernel(
    const int* __restrict__ EI, const float* __restrict__ EW,
    const float* __restrict__ S, float* __restrict__ Y)
{
    const int lane = threadIdx.x & 63;
    const int wid = (blockIdx.x * 256 + threadIdx.x) >> 6;
    const int nw = (gridDim.x * 256) >> 6;
    for (int e = wid; e < NE; e += nw) {
        int s = EI[e];
        int d = EI[NE + e];
        float w = EW[e];
        float v = S[(size_t)s * H + lane];
        unsafeAtomicAdd(&Y[(size_t)d * H + lane], w * v);
    }
}

__global__ __launch_bounds__(256) void scatter1_kernel(
    const int* __restrict__ EI, const float* __restrict__ EW,
    const float* __restrict__ S, float* __restrict__ Y)
{
    const int t = blockIdx.x * 256 + threadIdx.x;
    const int tot = gridDim.x * 256;
    for (int e = t; e < NE; e += tot) {
        int s = EI[e];
        int d = EI[NE + e];
        float w = EW[e];
        unsafeAtomicAdd(&Y[d], w * S[s]);
    }
}

__global__ __launch_bounds__(256) void readout_kernel(
    const float* __restrict__ Y3, float* __restrict__ body1,
    float* __restrict__ body2, unsigned int* __restrict__ keys)
{
    __shared__ unsigned int smax[4];
    const int tid = threadIdx.x;
    if (tid < 4) smax[tid] = 0u;
    __syncthreads();
    const int i = blockIdx.x * 256 + tid;
    if (i < NNODES) {
        float v = Y3[i];
        body1[i] = v;
        body2[i] = v;
        atomicMax(&smax[i / NGRAPH_NODES], fkey(v));
    }
    __syncthreads();
    if (tid < 4 && smax[tid]) atomicMax(&keys[tid], smax[tid]);
}

// ---------------------------------------------------------------------------
extern "C" void kernel_launch(void* const* d_in, const int* in_sizes, int n_in,
                              void* d_out, int out_size, void* d_ws, size_t ws_size,
                              hipStream_t stream)
{
    const float* x   = (const float*)d_in[0];
    const int*   ei  = (const int*)d_in[1];
    const float* ew  = (const float*)d_in[2];
    const int*   ei2 = (const int*)d_in[3];
    const float* ew2 = (const float*)d_in[4];
    const float* W[18];
    for (int i = 0; i < 18; ++i) W[i] = (const float*)d_in[6 + i];

    float* Y  = (float*)d_ws;                       // 200000 x 64
    float* S1 = Y + (size_t)NNODES * H;
    float* S2 = S1 + (size_t)NNODES * H;
    float* Y3 = S2 + (size_t)NNODES * H;            // 200000
    uint2* E1 = (uint2*)(Y3 + NNODES);              // NE uint2 (src, w)
    uint2* E2 = E1 + NE;
    unsigned int* keys = (unsigned int*)(E2 + NE);  // 4
    int* cnt1 = (int*)(keys + 4);                   // NNODES
    int* cnt2 = cnt1 + NNODES;                      // NNODES
    int* rp1  = cnt2 + NNODES;                      // NNODES+1
    int* rp2  = rp1 + NNODES + 1;                   // NNODES+1
    int* cur1 = rp2 + NNODES + 1;                   // NNODES
    int* cur2 = cur1 + NNODES;                      // NNODES
    size_t needed = (size_t)((char*)(cur2 + NNODES) - (char*)d_ws);

    float* out = (float*)d_out;   // [0..3]=graph max, then x twice

    if (ws_size >= needed) {
        // zero keys + histograms in one memset
        hipMemsetAsync(keys, 0, (size_t)(4 + 2 * NNODES) * sizeof(int), stream);

        // Counting sort by dst -> CSR (built once, reused by all 3 blocks)
        hist_full_kernel<<<1024, 256, 0, stream>>>(ei + NE,  cnt1);
        hist_full_kernel<<<1024, 256, 0, stream>>>(ei2 + NE, cnt2);
        scan200k_kernel<<<1, 1024, 0, stream>>>(cnt1, rp1, cur1);
        scan200k_kernel<<<1, 1024, 0, stream>>>(cnt2, rp2, cur2);
        place_kernel<<<2048, 256, 0, stream>>>(ei,  ew,  cur1, E1);
        place_kernel<<<2048, 256, 0, stream>>>(ei2, ew2, cur2, E2);

        // Block 1
        gemm3_kernel<128><<<NNODES / 32, 256, 0, stream>>>(
            x, W[0], W[1], W[2], W[3], W[4], W[5], Y, S1, S2);
        csr_accum64_kernel<<<6250, 256, 0, stream>>>(E1, rp1, E2, rp2, S1, S2, Y);

        // Block 2 (in-place on Y)
        gemm3_kernel<64><<<NNODES / 32, 256, 0, stream>>>(
            Y, W[6], W[7], W[8], W[9], W[10], W[11], Y, S1, S2);
        csr_accum64_kernel<<<6250, 256, 0, stream>>>(E1, rp1, E2, rp2, S1, S2, Y);

        // Block 3 (S1/S2 reused as [NNODES] scalars) + fused readout
        gemm3_out1_kernel<<<(NNODES + 255) / 256, 256, 0, stream>>>(
            Y, W[12], W[13], W[14], W[15], W[16], W[17], Y3, S1, S2);
        csr_accum1_readout_kernel<<<(NNODES + 255) / 256, 256, 0, stream>>>(
            E1, rp1, E2, rp2, S1, S2, Y3, out + 4, out + 4 + NNODES, keys);
        finalize_kernel<<<1, 64, 0, stream>>>(keys, out);
    } else {
        unsigned int* okeys = (unsigned int*)(Y3 + NNODES);
        hipMemsetAsync(okeys, 0, 4 * sizeof(unsigned int), stream);

        gemm3_kernel<128><<<NNODES / 32, 256, 0, stream>>>(
            x, W[0], W[1], W[2], W[3], W[4], W[5], Y, S1, S2);
        scatter64_kernel<<<2048, 256, 0, stream>>>(ei,  ew,  S1, Y);
        scatter64_kernel<<<2048, 256, 0, stream>>>(ei2, ew2, S2, Y);

        gemm3_kernel<64><<<NNODES / 32, 256, 0, stream>>>(
            Y, W[6], W[7], W[8], W[9], W[10], W[11], Y, S1, S2);
        scatter64_kernel<<<2048, 256, 0, stream>>>(ei,  ew,  S1, Y);
        scatter64_kernel<<<2048, 256, 0, stream>>>(ei2, ew2, S2, Y);

        gemm3_out1_kernel<<<(NNODES + 255) / 256, 256, 0, stream>>>(
            Y, W[12], W[13], W[14], W[15], W[16], W[17], Y3, S1, S2);
        scatter1_kernel<<<2048, 256, 0, stream>>>(ei,  ew,  S1, Y3);
        scatter1_kernel<<<2048, 256, 0, stream>>>(ei2, ew2, S2, Y3);

        readout_kernel<<<(NNODES + 255) / 256, 256, 0, stream>>>(
            Y3, out + 4, out + 4 + NNODES, okeys);
        finalize_kernel<<<1, 64, 0, stream>>>(okeys, out);
    }
}

// Round 5
// 1955.737 us; speedup vs baseline: 3.8565x; 1.4404x over previous
//
#include <hip/hip_runtime.h>
#include <hip/hip_bf16.h>

// Problem constants (fixed by the reference)
constexpr int NNODES = 200000;   // 4 graphs x 50000
constexpr int NGRAPH_NODES = 50000;
constexpr int NE = 3200000;
constexpr int H = 64;
constexpr int NBLK = (NNODES + 255) / 256;   // 782 scan blocks per array

// ---------------------------------------------------------------------------
// Fused 3-GEMM per inception block: Y = X@Wl + (Bl+B1+B2), S1 = X@W1, S2 = X@W2
// ---------------------------------------------------------------------------
template <int DI>
__global__ __launch_bounds__(256) void gemm3_kernel(
    const float* __restrict__ X,
    const float* __restrict__ Wl, const float* __restrict__ Bl,
    const float* __restrict__ W1, const float* __restrict__ B1,
    const float* __restrict__ W2, const float* __restrict__ B2,
    float* __restrict__ Y, float* __restrict__ S1, float* __restrict__ S2)
{
    __shared__ float xs[32][DI];
    const int tid = threadIdx.x;
    const int f = tid & 63;
    const int r = tid >> 6;
    const int base = blockIdx.x * 32;

    const float4* xg = reinterpret_cast<const float4*>(X + (size_t)base * DI);
    float4* xsv = reinterpret_cast<float4*>(&xs[0][0]);
    constexpr int NV = 32 * DI / 4;
    #pragma unroll
    for (int i = tid; i < NV; i += 256) xsv[i] = xg[i];
    __syncthreads();

    float accL[8], acc1[8], acc2[8];
    #pragma unroll
    for (int i = 0; i < 8; ++i) { accL[i] = 0.f; acc1[i] = 0.f; acc2[i] = 0.f; }

    for (int k = 0; k < DI; ++k) {
        float wl = Wl[k * H + f];
        float w1 = W1[k * H + f];
        float w2 = W2[k * H + f];
        #pragma unroll
        for (int i = 0; i < 8; ++i) {
            float xv = xs[r * 8 + i][k];
            accL[i] = fmaf(xv, wl, accL[i]);
            acc1[i] = fmaf(xv, w1, acc1[i]);
            acc2[i] = fmaf(xv, w2, acc2[i]);
        }
    }

    float bias = Bl[f] + B1[f] + B2[f];
    #pragma unroll
    for (int i = 0; i < 8; ++i) {
        size_t n = (size_t)(base + r * 8 + i);
        Y[n * H + f]  = accL[i] + bias;
        S1[n * H + f] = acc1[i];
        S2[n * H + f] = acc2[i];
    }
}

// ---------------------------------------------------------------------------
// Block 3 GEMM (DI=64 -> DO=1): three dot products per node.
// ---------------------------------------------------------------------------
__global__ __launch_bounds__(256) void gemm3_out1_kernel(
    const float* __restrict__ X,
    const float* __restrict__ Wl, const float* __restrict__ Bl,
    const float* __restrict__ W1, const float* __restrict__ B1,
    const float* __restrict__ W2, const float* __restrict__ B2,
    float* __restrict__ Y, float* __restrict__ S1, float* __restrict__ S2)
{
    __shared__ float wls[64], w1s[64], w2s[64];
    const int tid = threadIdx.x;
    if (tid < 64) { wls[tid] = Wl[tid]; w1s[tid] = W1[tid]; w2s[tid] = W2[tid]; }
    __syncthreads();
    const int n = blockIdx.x * 256 + tid;
    if (n >= NNODES) return;
    const float4* xr = reinterpret_cast<const float4*>(X + (size_t)n * H);
    float aL = 0.f, a1 = 0.f, a2 = 0.f;
    #pragma unroll
    for (int kv = 0; kv < 16; ++kv) {
        float4 xv = xr[kv];
        int k = kv * 4;
        aL = fmaf(xv.x, wls[k + 0], aL); a1 = fmaf(xv.x, w1s[k + 0], a1); a2 = fmaf(xv.x, w2s[k + 0], a2);
        aL = fmaf(xv.y, wls[k + 1], aL); a1 = fmaf(xv.y, w1s[k + 1], a1); a2 = fmaf(xv.y, w2s[k + 1], a2);
        aL = fmaf(xv.z, wls[k + 2], aL); a1 = fmaf(xv.z, w1s[k + 2], a1); a2 = fmaf(xv.z, w2s[k + 2], a2);
        aL = fmaf(xv.w, wls[k + 3], aL); a1 = fmaf(xv.w, w1s[k + 3], a1); a2 = fmaf(xv.w, w2s[k + 3], a2);
    }
    float bias = Bl[0] + B1[0] + B2[0];
    Y[n] = aL + bias; S1[n] = a1; S2[n] = a2;
}

// ---------------------------------------------------------------------------
// Counting sort by dst -> CSR. Histogram (both sets, gridDim.y=2).
// ---------------------------------------------------------------------------
__global__ __launch_bounds__(256) void hist_full_kernel(
    const int* __restrict__ dst1, const int* __restrict__ dst2,
    int* __restrict__ cnt1, int* __restrict__ cnt2)
{
    const int* dst = blockIdx.y ? dst2 : dst1;
    int* cnt = blockIdx.y ? cnt2 : cnt1;
    const int t = blockIdx.x * 256 + threadIdx.x;
    const int tot = gridDim.x * 256;
    for (int e = t; e < NE; e += tot) atomicAdd(&cnt[dst[e]], 1);
}

// Hierarchical exclusive scan over 200k counts, both sets per launch.
// Pass A: per-block (256-wide) exclusive scan IN-PLACE on cnt; block sums out.
__global__ __launch_bounds__(256) void scan_pass_a(
    int* __restrict__ cnt1, int* __restrict__ cnt2, int* __restrict__ bs)
{
    const int set = blockIdx.y;
    int* cnt = set ? cnt2 : cnt1;
    __shared__ int tmp[256];
    const int i = blockIdx.x * 256 + threadIdx.x;
    int v = (i < NNODES) ? cnt[i] : 0;
    tmp[threadIdx.x] = v;
    __syncthreads();
    #pragma unroll
    for (int off = 1; off < 256; off <<= 1) {
        int t = (threadIdx.x >= off) ? tmp[threadIdx.x - off] : 0;
        __syncthreads();
        tmp[threadIdx.x] += t;
        __syncthreads();
    }
    if (i < NNODES) cnt[i] = tmp[threadIdx.x] - v;   // exclusive within block
    if (threadIdx.x == 255) bs[set * NBLK + blockIdx.x] = tmp[255];
}

// Pass B: scan the 782 block sums (one block per set), in-place exclusive.
__global__ __launch_bounds__(1024) void scan_pass_b(
    int* __restrict__ bs, int* __restrict__ tot)
{
    __shared__ int tmp[1024];
    int* b = bs + blockIdx.x * NBLK;
    const int t = threadIdx.x;
    int v = (t < NBLK) ? b[t] : 0;
    tmp[t] = v;
    __syncthreads();
    for (int off = 1; off < 1024; off <<= 1) {
        int u = (t >= off) ? tmp[t - off] : 0;
        __syncthreads();
        tmp[t] += u;
        __syncthreads();
    }
    if (t < NBLK) b[t] = tmp[t] - v;
    if (t == 1023) tot[blockIdx.x] = tmp[1023];
}

// Pass C: add block offsets -> row_ptr + cursor.
__global__ __launch_bounds__(256) void scan_pass_c(
    const int* __restrict__ cnt1, const int* __restrict__ cnt2,
    const int* __restrict__ bs, const int* __restrict__ tot,
    int* __restrict__ rp1, int* __restrict__ rp2,
    int* __restrict__ cur1, int* __restrict__ cur2)
{
    const int set = blockIdx.y;
    const int* ex = set ? cnt2 : cnt1;
    int* rp = set ? rp2 : rp1;
    int* cur = set ? cur2 : cur1;
    const int off = bs[set * NBLK + blockIdx.x];
    const int i = blockIdx.x * 256 + threadIdx.x;
    if (i < NNODES) {
        int v = ex[i] + off;
        rp[i] = v;
        cur[i] = v;
    }
    if (blockIdx.x == 0 && threadIdx.x == 0) rp[NNODES] = tot[set];
}

__global__ __launch_bounds__(256) void place_kernel(
    const int* __restrict__ EI, const float* __restrict__ EW,
    int* __restrict__ cursor, uint2* __restrict__ sorted)
{
    const int t = blockIdx.x * 256 + threadIdx.x;
    const int tot = gridDim.x * 256;
    for (int e = t; e < NE; e += tot) {
        int s = EI[e];
        int d = EI[NE + e];
        int pos = atomicAdd(&cursor[d], 1);
        sorted[pos] = make_uint2((unsigned)s, __float_as_uint(EW[e]));
    }
}

// ---------------------------------------------------------------------------
// CSR SpMV aggregation, 64 features: one wave per dst row, 8 rows/wave.
// No atomics: wave exclusively owns its rows. Both edge sets in one pass.
// ---------------------------------------------------------------------------
__global__ __launch_bounds__(256) void csr_accum64_kernel(
    const uint2* __restrict__ E1, const int* __restrict__ rp1,
    const uint2* __restrict__ E2, const int* __restrict__ rp2,
    const float* __restrict__ S1, const float* __restrict__ S2,
    float* __restrict__ Y)
{
    const int lane = threadIdx.x & 63;
    const int wid = (blockIdx.x * 256 + threadIdx.x) >> 6;
    const int r0 = wid * 8;   // 25000 waves x 8 rows = 200000

    for (int r = r0; r < r0 + 8; ++r) {
        float acc = 0.f;
        {
            const int lo = rp1[r], hi = rp1[r + 1];
            int e = lo;
            for (; e + 4 <= hi; e += 4) {
                uint2 p0 = E1[e], p1 = E1[e + 1], p2 = E1[e + 2], p3 = E1[e + 3];
                float v0 = S1[(size_t)p0.x * H + lane];
                float v1 = S1[(size_t)p1.x * H + lane];
                float v2 = S1[(size_t)p2.x * H + lane];
                float v3 = S1[(size_t)p3.x * H + lane];
                acc = fmaf(__uint_as_float(p0.y), v0, acc);
                acc = fmaf(__uint_as_float(p1.y), v1, acc);
                acc = fmaf(__uint_as_float(p2.y), v2, acc);
                acc = fmaf(__uint_as_float(p3.y), v3, acc);
            }
            for (; e < hi; ++e) {
                uint2 p = E1[e];
                acc = fmaf(__uint_as_float(p.y), S1[(size_t)p.x * H + lane], acc);
            }
        }
        {
            const int lo = rp2[r], hi = rp2[r + 1];
            int e = lo;
            for (; e + 4 <= hi; e += 4) {
                uint2 p0 = E2[e], p1 = E2[e + 1], p2 = E2[e + 2], p3 = E2[e + 3];
                float v0 = S2[(size_t)p0.x * H + lane];
                float v1 = S2[(size_t)p1.x * H + lane];
                float v2 = S2[(size_t)p2.x * H + lane];
                float v3 = S2[(size_t)p3.x * H + lane];
                acc = fmaf(__uint_as_float(p0.y), v0, acc);
                acc = fmaf(__uint_as_float(p1.y), v1, acc);
                acc = fmaf(__uint_as_float(p2.y), v2, acc);
                acc = fmaf(__uint_as_float(p3.y), v3, acc);
            }
            for (; e < hi; ++e) {
                uint2 p = E2[e];
                acc = fmaf(__uint_as_float(p.y), S2[(size_t)p.x * H + lane], acc);
            }
        }
        Y[(size_t)r * H + lane] += acc;
    }
}

// ---------------------------------------------------------------------------
// Block-3 CSR aggregation (scalar) + fused readout.
// ---------------------------------------------------------------------------
__device__ __forceinline__ unsigned fkey(float v) {
    unsigned u = __float_as_uint(v);
    return (u & 0x80000000u) ? ~u : (u | 0x80000000u);
}

__global__ __launch_bounds__(256) void csr_accum1_readout_kernel(
    const uint2* __restrict__ E1, const int* __restrict__ rp1,
    const uint2* __restrict__ E2, const int* __restrict__ rp2,
    const float* __restrict__ s1, const float* __restrict__ s2,
    const float* __restrict__ Y3,
    float* __restrict__ body1, float* __restrict__ body2,
    unsigned int* __restrict__ keys)
{
    __shared__ unsigned int smax[4];
    const int tid = threadIdx.x;
    if (tid < 4) smax[tid] = 0u;
    __syncthreads();
    const int r = blockIdx.x * 256 + tid;
    if (r < NNODES) {
        float acc = Y3[r];
        for (int e = rp1[r]; e < rp1[r + 1]; ++e) {
            uint2 p = E1[e];
            acc = fmaf(__uint_as_float(p.y), s1[p.x], acc);
        }
        for (int e = rp2[r]; e < rp2[r + 1]; ++e) {
            uint2 p = E2[e];
            acc = fmaf(__uint_as_float(p.y), s2[p.x], acc);
        }
        body1[r] = acc;
        body2[r] = acc;
        atomicMax(&smax[r / NGRAPH_NODES], fkey(acc));
    }
    __syncthreads();
    if (tid < 4 && smax[tid]) atomicMax(&keys[tid], smax[tid]);
}

__global__ void finalize_kernel(const unsigned int* __restrict__ keys,
                                float* __restrict__ out)
{
    int i = threadIdx.x;
    if (i < 4) {
        unsigned k = keys[i];
        unsigned u = (k & 0x80000000u) ? (k ^ 0x80000000u) : ~k;
        out[i] = __uint_as_float(u);
    }
}

// ---------------------------------------------------------------------------
// Fallback (atomic) scatters — used only if ws_size is too small.
// ---------------------------------------------------------------------------
__global__ __launch_bounds__(256) void scatter64_kernel(
    const int* __restrict__ EI, const float* __restrict__ EW,
    const float* __restrict__ S, float* __restrict__ Y)
{
    const int lane = threadIdx.x & 63;
    const int wid = (blockIdx.x * 256 + threadIdx.x) >> 6;
    const int nw = (gridDim.x * 256) >> 6;
    for (int e = wid; e < NE; e += nw) {
        int s = EI[e];
        int d = EI[NE + e];
        float w = EW[e];
        float v = S[(size_t)s * H + lane];
        unsafeAtomicAdd(&Y[(size_t)d * H + lane], w * v);
    }
}

__global__ __launch_bounds__(256) void scatter1_kernel(
    const int* __restrict__ EI, const float* __restrict__ EW,
    const float* __restrict__ S, float* __restrict__ Y)
{
    const int t = blockIdx.x * 256 + threadIdx.x;
    const int tot = gridDim.x * 256;
    for (int e = t; e < NE; e += tot) {
        int s = EI[e];
        int d = EI[NE + e];
        float w = EW[e];
        unsafeAtomicAdd(&Y[d], w * S[s]);
    }
}

__global__ __launch_bounds__(256) void readout_kernel(
    const float* __restrict__ Y3, float* __restrict__ body1,
    float* __restrict__ body2, unsigned int* __restrict__ keys)
{
    __shared__ unsigned int smax[4];
    const int tid = threadIdx.x;
    if (tid < 4) smax[tid] = 0u;
    __syncthreads();
    const int i = blockIdx.x * 256 + tid;
    if (i < NNODES) {
        float v = Y3[i];
        body1[i] = v;
        body2[i] = v;
        atomicMax(&smax[i / NGRAPH_NODES], fkey(v));
    }
    __syncthreads();
    if (tid < 4 && smax[tid]) atomicMax(&keys[tid], smax[tid]);
}

// ---------------------------------------------------------------------------
extern "C" void kernel_launch(void* const* d_in, const int* in_sizes, int n_in,
                              void* d_out, int out_size, void* d_ws, size_t ws_size,
                              hipStream_t stream)
{
    const float* x   = (const float*)d_in[0];
    const int*   ei  = (const int*)d_in[1];
    const float* ew  = (const float*)d_in[2];
    const int*   ei2 = (const int*)d_in[3];
    const float* ew2 = (const float*)d_in[4];
    const float* W[18];
    for (int i = 0; i < 18; ++i) W[i] = (const float*)d_in[6 + i];

    float* Y  = (float*)d_ws;                       // 200000 x 64
    float* S1 = Y + (size_t)NNODES * H;
    float* S2 = S1 + (size_t)NNODES * H;
    float* Y3 = S2 + (size_t)NNODES * H;            // 200000
    uint2* E1 = (uint2*)(Y3 + NNODES);              // NE uint2 (src, w)
    uint2* E2 = E1 + NE;
    unsigned int* keys = (unsigned int*)(E2 + NE);  // 4
    int* cnt1 = (int*)(keys + 4);                   // NNODES
    int* cnt2 = cnt1 + NNODES;                      // NNODES
    int* rp1  = cnt2 + NNODES;                      // NNODES+1
    int* rp2  = rp1 + NNODES + 1;                   // NNODES+1
    int* cur1 = rp2 + NNODES + 1;                   // NNODES
    int* cur2 = cur1 + NNODES;                      // NNODES
    int* bs   = cur2 + NNODES;                      // 2*NBLK
    int* tot  = bs + 2 * NBLK;                      // 2
    size_t needed = (size_t)((char*)(tot + 2) - (char*)d_ws);

    float* out = (float*)d_out;   // [0..3]=graph max, then x twice

    if (ws_size >= needed) {
        // zero keys + histograms in one memset
        hipMemsetAsync(keys, 0, (size_t)(4 + 2 * NNODES) * sizeof(int), stream);

        // Counting sort by dst -> CSR (built once, reused by all 3 blocks)
        hist_full_kernel<<<dim3(1024, 2), 256, 0, stream>>>(ei + NE, ei2 + NE, cnt1, cnt2);
        scan_pass_a<<<dim3(NBLK, 2), 256, 0, stream>>>(cnt1, cnt2, bs);
        scan_pass_b<<<2, 1024, 0, stream>>>(bs, tot);
        scan_pass_c<<<dim3(NBLK, 2), 256, 0, stream>>>(cnt1, cnt2, bs, tot,
                                                       rp1, rp2, cur1, cur2);
        place_kernel<<<2048, 256, 0, stream>>>(ei,  ew,  cur1, E1);
        place_kernel<<<2048, 256, 0, stream>>>(ei2, ew2, cur2, E2);

        // Block 1
        gemm3_kernel<128><<<NNODES / 32, 256, 0, stream>>>(
            x, W[0], W[1], W[2], W[3], W[4], W[5], Y, S1, S2);
        csr_accum64_kernel<<<6250, 256, 0, stream>>>(E1, rp1, E2, rp2, S1, S2, Y);

        // Block 2 (in-place on Y)
        gemm3_kernel<64><<<NNODES / 32, 256, 0, stream>>>(
            Y, W[6], W[7], W[8], W[9], W[10], W[11], Y, S1, S2);
        csr_accum64_kernel<<<6250, 256, 0, stream>>>(E1, rp1, E2, rp2, S1, S2, Y);

        // Block 3 (S1/S2 reused as [NNODES] scalars) + fused readout
        gemm3_out1_kernel<<<(NNODES + 255) / 256, 256, 0, stream>>>(
            Y, W[12], W[13], W[14], W[15], W[16], W[17], Y3, S1, S2);
        csr_accum1_readout_kernel<<<(NNODES + 255) / 256, 256, 0, stream>>>(
            E1, rp1, E2, rp2, S1, S2, Y3, out + 4, out + 4 + NNODES, keys);
        finalize_kernel<<<1, 64, 0, stream>>>(keys, out);
    } else {
        unsigned int* okeys = (unsigned int*)(Y3 + NNODES);
        hipMemsetAsync(okeys, 0, 4 * sizeof(unsigned int), stream);

        gemm3_kernel<128><<<NNODES / 32, 256, 0, stream>>>(
            x, W[0], W[1], W[2], W[3], W[4], W[5], Y, S1, S2);
        scatter64_kernel<<<2048, 256, 0, stream>>>(ei,  ew,  S1, Y);
        scatter64_kernel<<<2048, 256, 0, stream>>>(ei2, ew2, S2, Y);

        gemm3_kernel<64><<<NNODES / 32, 256, 0, stream>>>(
            Y, W[6], W[7], W[8], W[9], W[10], W[11], Y, S1, S2);
        scatter64_kernel<<<2048, 256, 0, stream>>>(ei,  ew,  S1, Y);
        scatter64_kernel<<<2048, 256, 0, stream>>>(ei2, ew2, S2, Y);

        gemm3_out1_kernel<<<(NNODES + 255) / 256, 256, 0, stream>>>(
            Y, W[12], W[13], W[14], W[15], W[16], W[17], Y3, S1, S2);
        scatter1_kernel<<<2048, 256, 0, stream>>>(ei,  ew,  S1, Y3);
        scatter1_kernel<<<2048, 256, 0, stream>>>(ei2, ew2, S2, Y3);

        readout_kernel<<<(NNODES + 255) / 256, 256, 0, stream>>>(
            Y3, out + 4, out + 4 + NNODES, okeys);
        finalize_kernel<<<1, 64, 0, stream>>>(okeys, out);
    }
}

// Round 6
// 1816.725 us; speedup vs baseline: 4.1516x; 1.0765x over previous
//
#include <hip/hip_runtime.h>
#include <hip/hip_bf16.h>
#include <hip/hip_fp16.h>

// Problem constants (fixed by the reference)
constexpr int NNODES = 200000;   // 4 graphs x 50000
constexpr int NGRAPH_NODES = 50000;
constexpr int NE = 3200000;
constexpr int H = 64;
constexpr int NBLK = (NNODES + 255) / 256;   // 782 scan blocks per array

// ---------------------------------------------------------------------------
// Fused 3-GEMM per inception block: Y = X@Wl + (Bl+B1+B2), S1 = X@W1, S2 = X@W2
// TS = storage type for S1/S2 (fp16 on the fast path to halve gather bytes).
// ---------------------------------------------------------------------------
template <int DI, typename TS>
__global__ __launch_bounds__(256) void gemm3_kernel(
    const float* __restrict__ X,
    const float* __restrict__ Wl, const float* __restrict__ Bl,
    const float* __restrict__ W1, const float* __restrict__ B1,
    const float* __restrict__ W2, const float* __restrict__ B2,
    float* __restrict__ Y, TS* __restrict__ S1, TS* __restrict__ S2)
{
    __shared__ float xs[32][DI];
    const int tid = threadIdx.x;
    const int f = tid & 63;
    const int r = tid >> 6;
    const int base = blockIdx.x * 32;

    const float4* xg = reinterpret_cast<const float4*>(X + (size_t)base * DI);
    float4* xsv = reinterpret_cast<float4*>(&xs[0][0]);
    constexpr int NV = 32 * DI / 4;
    #pragma unroll
    for (int i = tid; i < NV; i += 256) xsv[i] = xg[i];
    __syncthreads();

    float accL[8], acc1[8], acc2[8];
    #pragma unroll
    for (int i = 0; i < 8; ++i) { accL[i] = 0.f; acc1[i] = 0.f; acc2[i] = 0.f; }

    for (int k = 0; k < DI; ++k) {
        float wl = Wl[k * H + f];
        float w1 = W1[k * H + f];
        float w2 = W2[k * H + f];
        #pragma unroll
        for (int i = 0; i < 8; ++i) {
            float xv = xs[r * 8 + i][k];
            accL[i] = fmaf(xv, wl, accL[i]);
            acc1[i] = fmaf(xv, w1, acc1[i]);
            acc2[i] = fmaf(xv, w2, acc2[i]);
        }
    }

    float bias = Bl[f] + B1[f] + B2[f];
    #pragma unroll
    for (int i = 0; i < 8; ++i) {
        size_t n = (size_t)(base + r * 8 + i);
        Y[n * H + f]  = accL[i] + bias;
        S1[n * H + f] = (TS)acc1[i];
        S2[n * H + f] = (TS)acc2[i];
    }
}

// ---------------------------------------------------------------------------
// Block 3 GEMM (DI=64 -> DO=1): three dot products per node.
// ---------------------------------------------------------------------------
__global__ __launch_bounds__(256) void gemm3_out1_kernel(
    const float* __restrict__ X,
    const float* __restrict__ Wl, const float* __restrict__ Bl,
    const float* __restrict__ W1, const float* __restrict__ B1,
    const float* __restrict__ W2, const float* __restrict__ B2,
    float* __restrict__ Y, float* __restrict__ S1, float* __restrict__ S2)
{
    __shared__ float wls[64], w1s[64], w2s[64];
    const int tid = threadIdx.x;
    if (tid < 64) { wls[tid] = Wl[tid]; w1s[tid] = W1[tid]; w2s[tid] = W2[tid]; }
    __syncthreads();
    const int n = blockIdx.x * 256 + tid;
    if (n >= NNODES) return;
    const float4* xr = reinterpret_cast<const float4*>(X + (size_t)n * H);
    float aL = 0.f, a1 = 0.f, a2 = 0.f;
    #pragma unroll
    for (int kv = 0; kv < 16; ++kv) {
        float4 xv = xr[kv];
        int k = kv * 4;
        aL = fmaf(xv.x, wls[k + 0], aL); a1 = fmaf(xv.x, w1s[k + 0], a1); a2 = fmaf(xv.x, w2s[k + 0], a2);
        aL = fmaf(xv.y, wls[k + 1], aL); a1 = fmaf(xv.y, w1s[k + 1], a1); a2 = fmaf(xv.y, w2s[k + 1], a2);
        aL = fmaf(xv.z, wls[k + 2], aL); a1 = fmaf(xv.z, w1s[k + 2], a1); a2 = fmaf(xv.z, w2s[k + 2], a2);
        aL = fmaf(xv.w, wls[k + 3], aL); a1 = fmaf(xv.w, w1s[k + 3], a1); a2 = fmaf(xv.w, w2s[k + 3], a2);
    }
    float bias = Bl[0] + B1[0] + B2[0];
    Y[n] = aL + bias; S1[n] = a1; S2[n] = a2;
}

// ---------------------------------------------------------------------------
// Counting sort by dst -> CSR. Histogram (both sets, gridDim.y=2), int4 reads.
// ---------------------------------------------------------------------------
__global__ __launch_bounds__(256) void hist_full_kernel(
    const int* __restrict__ dst1, const int* __restrict__ dst2,
    int* __restrict__ cnt1, int* __restrict__ cnt2)
{
    const int* dst = blockIdx.y ? dst2 : dst1;
    int* cnt = blockIdx.y ? cnt2 : cnt1;
    const int t = blockIdx.x * 256 + threadIdx.x;
    const int tot = gridDim.x * 256;
    const int4* d4 = reinterpret_cast<const int4*>(dst);
    for (int q = t; q < NE / 4; q += tot) {
        int4 v = d4[q];
        atomicAdd(&cnt[v.x], 1);
        atomicAdd(&cnt[v.y], 1);
        atomicAdd(&cnt[v.z], 1);
        atomicAdd(&cnt[v.w], 1);
    }
}

// Hierarchical exclusive scan over 200k counts, both sets per launch.
__global__ __launch_bounds__(256) void scan_pass_a(
    int* __restrict__ cnt1, int* __restrict__ cnt2, int* __restrict__ bs)
{
    const int set = blockIdx.y;
    int* cnt = set ? cnt2 : cnt1;
    __shared__ int tmp[256];
    const int i = blockIdx.x * 256 + threadIdx.x;
    int v = (i < NNODES) ? cnt[i] : 0;
    tmp[threadIdx.x] = v;
    __syncthreads();
    #pragma unroll
    for (int off = 1; off < 256; off <<= 1) {
        int t = (threadIdx.x >= off) ? tmp[threadIdx.x - off] : 0;
        __syncthreads();
        tmp[threadIdx.x] += t;
        __syncthreads();
    }
    if (i < NNODES) cnt[i] = tmp[threadIdx.x] - v;   // exclusive within block
    if (threadIdx.x == 255) bs[set * NBLK + blockIdx.x] = tmp[255];
}

__global__ __launch_bounds__(1024) void scan_pass_b(
    int* __restrict__ bs, int* __restrict__ tot)
{
    __shared__ int tmp[1024];
    int* b = bs + blockIdx.x * NBLK;
    const int t = threadIdx.x;
    int v = (t < NBLK) ? b[t] : 0;
    tmp[t] = v;
    __syncthreads();
    for (int off = 1; off < 1024; off <<= 1) {
        int u = (t >= off) ? tmp[t - off] : 0;
        __syncthreads();
        tmp[t] += u;
        __syncthreads();
    }
    if (t < NBLK) b[t] = tmp[t] - v;
    if (t == 1023) tot[blockIdx.x] = tmp[1023];
}

__global__ __launch_bounds__(256) void scan_pass_c(
    const int* __restrict__ cnt1, const int* __restrict__ cnt2,
    const int* __restrict__ bs, const int* __restrict__ tot,
    int* __restrict__ rp1, int* __restrict__ rp2,
    int* __restrict__ cur1, int* __restrict__ cur2)
{
    const int set = blockIdx.y;
    const int* ex = set ? cnt2 : cnt1;
    int* rp = set ? rp2 : rp1;
    int* cur = set ? cur2 : cur1;
    const int off = bs[set * NBLK + blockIdx.x];
    const int i = blockIdx.x * 256 + threadIdx.x;
    if (i < NNODES) {
        int v = ex[i] + off;
        rp[i] = v;
        cur[i] = v;
    }
    if (blockIdx.x == 0 && threadIdx.x == 0) rp[NNODES] = tot[set];
}

// Place both edge sets (gridDim.y selects set).
__global__ __launch_bounds__(256) void place_kernel(
    const int* __restrict__ ei1, const float* __restrict__ ew1,
    const int* __restrict__ ei2, const float* __restrict__ ew2,
    int* __restrict__ cur1, int* __restrict__ cur2,
    uint2* __restrict__ sorted1, uint2* __restrict__ sorted2)
{
    const int set = blockIdx.y;
    const int* EI = set ? ei2 : ei1;
    const float* EW = set ? ew2 : ew1;
    int* cursor = set ? cur2 : cur1;
    uint2* sorted = set ? sorted2 : sorted1;
    const int t = blockIdx.x * 256 + threadIdx.x;
    const int tot = gridDim.x * 256;
    for (int e = t; e < NE; e += tot) {
        int s = EI[e];
        int d = EI[NE + e];
        int pos = atomicAdd(&cursor[d], 1);
        sorted[pos] = make_uint2((unsigned)s, __float_as_uint(EW[e]));
    }
}

// ---------------------------------------------------------------------------
// CSR SpMV aggregation, 64 features, fp16 source values.
// One wave per dst row, 8 rows/wave; row extents prefetched; 8-deep unroll.
// ---------------------------------------------------------------------------
__global__ __launch_bounds__(256) void csr_accum64_kernel(
    const uint2* __restrict__ E1, const int* __restrict__ rp1,
    const uint2* __restrict__ E2, const int* __restrict__ rp2,
    const __half* __restrict__ S1, const __half* __restrict__ S2,
    float* __restrict__ Y)
{
    const int lane = threadIdx.x & 63;
    const int wid = (blockIdx.x * 256 + threadIdx.x) >> 6;
    const int r0 = wid * 8;   // 25000 waves x 8 rows = 200000

    int b1[9], b2[9];
    #pragma unroll
    for (int i = 0; i < 9; ++i) b1[i] = rp1[r0 + i];
    #pragma unroll
    for (int i = 0; i < 9; ++i) b2[i] = rp2[r0 + i];

    #pragma unroll 1
    for (int r = 0; r < 8; ++r) {
        float acc = 0.f;
        {
            int e = b1[r];
            const int hi = b1[r + 1];
            for (; e + 8 <= hi; e += 8) {
                uint2 p[8];
                float v[8];
                #pragma unroll
                for (int j = 0; j < 8; ++j) p[j] = E1[e + j];
                #pragma unroll
                for (int j = 0; j < 8; ++j)
                    v[j] = __half2float(S1[(size_t)p[j].x * H + lane]);
                #pragma unroll
                for (int j = 0; j < 8; ++j)
                    acc = fmaf(__uint_as_float(p[j].y), v[j], acc);
            }
            for (; e < hi; ++e) {
                uint2 p = E1[e];
                acc = fmaf(__uint_as_float(p.y),
                           __half2float(S1[(size_t)p.x * H + lane]), acc);
            }
        }
        {
            int e = b2[r];
            const int hi = b2[r + 1];
            for (; e + 8 <= hi; e += 8) {
                uint2 p[8];
                float v[8];
                #pragma unroll
                for (int j = 0; j < 8; ++j) p[j] = E2[e + j];
                #pragma unroll
                for (int j = 0; j < 8; ++j)
                    v[j] = __half2float(S2[(size_t)p[j].x * H + lane]);
                #pragma unroll
                for (int j = 0; j < 8; ++j)
                    acc = fmaf(__uint_as_float(p[j].y), v[j], acc);
            }
            for (; e < hi; ++e) {
                uint2 p = E2[e];
                acc = fmaf(__uint_as_float(p.y),
                           __half2float(S2[(size_t)p.x * H + lane]), acc);
            }
        }
        Y[(size_t)(r0 + r) * H + lane] += acc;
    }
}

// ---------------------------------------------------------------------------
// Block-3 CSR aggregation (scalar, fp32) + fused readout.
// ---------------------------------------------------------------------------
__device__ __forceinline__ unsigned fkey(float v) {
    unsigned u = __float_as_uint(v);
    return (u & 0x80000000u) ? ~u : (u | 0x80000000u);
}

__global__ __launch_bounds__(256) void csr_accum1_readout_kernel(
    const uint2* __restrict__ E1, const int* __restrict__ rp1,
    const uint2* __restrict__ E2, const int* __restrict__ rp2,
    const float* __restrict__ s1, const float* __restrict__ s2,
    const float* __restrict__ Y3,
    float* __restrict__ body1, float* __restrict__ body2,
    unsigned int* __restrict__ keys)
{
    __shared__ unsigned int smax[4];
    const int tid = threadIdx.x;
    if (tid < 4) smax[tid] = 0u;
    __syncthreads();
    const int r = blockIdx.x * 256 + tid;
    if (r < NNODES) {
        float acc = Y3[r];
        for (int e = rp1[r]; e < rp1[r + 1]; ++e) {
            uint2 p = E1[e];
            acc = fmaf(__uint_as_float(p.y), s1[p.x], acc);
        }
        for (int e = rp2[r]; e < rp2[r + 1]; ++e) {
            uint2 p = E2[e];
            acc = fmaf(__uint_as_float(p.y), s2[p.x], acc);
        }
        body1[r] = acc;
        body2[r] = acc;
        atomicMax(&smax[r / NGRAPH_NODES], fkey(acc));
    }
    __syncthreads();
    if (tid < 4 && smax[tid]) atomicMax(&keys[tid], smax[tid]);
}

__global__ void finalize_kernel(const unsigned int* __restrict__ keys,
                                float* __restrict__ out)
{
    int i = threadIdx.x;
    if (i < 4) {
        unsigned k = keys[i];
        unsigned u = (k & 0x80000000u) ? (k ^ 0x80000000u) : ~k;
        out[i] = __uint_as_float(u);
    }
}

// ---------------------------------------------------------------------------
// Fallback (atomic) scatters — used only if ws_size is too small.
// ---------------------------------------------------------------------------
__global__ __launch_bounds__(256) void scatter64_kernel(
    const int* __restrict__ EI, const float* __restrict__ EW,
    const float* __restrict__ S, float* __restrict__ Y)
{
    const int lane = threadIdx.x & 63;
    const int wid = (blockIdx.x * 256 + threadIdx.x) >> 6;
    const int nw = (gridDim.x * 256) >> 6;
    for (int e = wid; e < NE; e += nw) {
        int s = EI[e];
        int d = EI[NE + e];
        float w = EW[e];
        float v = S[(size_t)s * H + lane];
        unsafeAtomicAdd(&Y[(size_t)d * H + lane], w * v);
    }
}

__global__ __launch_bounds__(256) void scatter1_kernel(
    const int* __restrict__ EI, const float* __restrict__ EW,
    const float* __restrict__ S, float* __restrict__ Y)
{
    const int t = blockIdx.x * 256 + threadIdx.x;
    const int tot = gridDim.x * 256;
    for (int e = t; e < NE; e += tot) {
        int s = EI[e];
        int d = EI[NE + e];
        float w = EW[e];
        unsafeAtomicAdd(&Y[d], w * S[s]);
    }
}

__global__ __launch_bounds__(256) void readout_kernel(
    const float* __restrict__ Y3, float* __restrict__ body1,
    float* __restrict__ body2, unsigned int* __restrict__ keys)
{
    __shared__ unsigned int smax[4];
    const int tid = threadIdx.x;
    if (tid < 4) smax[tid] = 0u;
    __syncthreads();
    const int i = blockIdx.x * 256 + tid;
    if (i < NNODES) {
        float v = Y3[i];
        body1[i] = v;
        body2[i] = v;
        atomicMax(&smax[i / NGRAPH_NODES], fkey(v));
    }
    __syncthreads();
    if (tid < 4 && smax[tid]) atomicMax(&keys[tid], smax[tid]);
}

// ---------------------------------------------------------------------------
extern "C" void kernel_launch(void* const* d_in, const int* in_sizes, int n_in,
                              void* d_out, int out_size, void* d_ws, size_t ws_size,
                              hipStream_t stream)
{
    const float* x   = (const float*)d_in[0];
    const int*   ei  = (const int*)d_in[1];
    const float* ew  = (const float*)d_in[2];
    const int*   ei2 = (const int*)d_in[3];
    const float* ew2 = (const float*)d_in[4];
    const float* W[18];
    for (int i = 0; i < 18; ++i) W[i] = (const float*)d_in[6 + i];

    // S1/S2 sized for the fp32 fallback (fp16 fast path uses half the space)
    float* Y  = (float*)d_ws;                       // 200000 x 64 f32
    float* S1 = Y + (size_t)NNODES * H;             // 200000 x 64 f32 (or f16)
    float* S2 = S1 + (size_t)NNODES * H;
    float* Y3 = S2 + (size_t)NNODES * H;            // 200000 f32
    uint2* E1 = (uint2*)(Y3 + NNODES);              // NE uint2 (src, w)
    uint2* E2 = E1 + NE;
    unsigned int* keys = (unsigned int*)(E2 + NE);  // 4
    int* cnt1 = (int*)(keys + 4);                   // NNODES
    int* cnt2 = cnt1 + NNODES;                      // NNODES
    int* rp1  = cnt2 + NNODES;                      // NNODES+1
    int* rp2  = rp1 + NNODES + 1;                   // NNODES+1
    int* cur1 = rp2 + NNODES + 1;                   // NNODES
    int* cur2 = cur1 + NNODES;                      // NNODES
    int* bs   = cur2 + NNODES;                      // 2*NBLK
    int* tot  = bs + 2 * NBLK;                      // 2
    size_t needed = (size_t)((char*)(tot + 2) - (char*)d_ws);

    __half* hS1 = (__half*)S1;
    __half* hS2 = (__half*)S2;

    float* out = (float*)d_out;   // [0..3]=graph max, then x twice

    if (ws_size >= needed) {
        // zero keys + histograms in one memset
        hipMemsetAsync(keys, 0, (size_t)(4 + 2 * NNODES) * sizeof(int), stream);

        // Counting sort by dst -> CSR (built once, reused by all 3 blocks)
        hist_full_kernel<<<dim3(1024, 2), 256, 0, stream>>>(ei + NE, ei2 + NE, cnt1, cnt2);
        scan_pass_a<<<dim3(NBLK, 2), 256, 0, stream>>>(cnt1, cnt2, bs);
        scan_pass_b<<<2, 1024, 0, stream>>>(bs, tot);
        scan_pass_c<<<dim3(NBLK, 2), 256, 0, stream>>>(cnt1, cnt2, bs, tot,
                                                       rp1, rp2, cur1, cur2);
        place_kernel<<<dim3(2048, 2), 256, 0, stream>>>(ei, ew, ei2, ew2,
                                                        cur1, cur2, E1, E2);

        // Block 1
        gemm3_kernel<128, __half><<<NNODES / 32, 256, 0, stream>>>(
            x, W[0], W[1], W[2], W[3], W[4], W[5], Y, hS1, hS2);
        csr_accum64_kernel<<<6250, 256, 0, stream>>>(E1, rp1, E2, rp2, hS1, hS2, Y);

        // Block 2 (in-place on Y)
        gemm3_kernel<64, __half><<<NNODES / 32, 256, 0, stream>>>(
            Y, W[6], W[7], W[8], W[9], W[10], W[11], Y, hS1, hS2);
        csr_accum64_kernel<<<6250, 256, 0, stream>>>(E1, rp1, E2, rp2, hS1, hS2, Y);

        // Block 3 (S1/S2 reused as [NNODES] f32 scalars) + fused readout
        gemm3_out1_kernel<<<(NNODES + 255) / 256, 256, 0, stream>>>(
            Y, W[12], W[13], W[14], W[15], W[16], W[17], Y3, S1, S2);
        csr_accum1_readout_kernel<<<(NNODES + 255) / 256, 256, 0, stream>>>(
            E1, rp1, E2, rp2, S1, S2, Y3, out + 4, out + 4 + NNODES, keys);
        finalize_kernel<<<1, 64, 0, stream>>>(keys, out);
    } else {
        unsigned int* okeys = (unsigned int*)(Y3 + NNODES);
        hipMemsetAsync(okeys, 0, 4 * sizeof(unsigned int), stream);

        gemm3_kernel<128, float><<<NNODES / 32, 256, 0, stream>>>(
            x, W[0], W[1], W[2], W[3], W[4], W[5], Y, S1, S2);
        scatter64_kernel<<<2048, 256, 0, stream>>>(ei,  ew,  S1, Y);
        scatter64_kernel<<<2048, 256, 0, stream>>>(ei2, ew2, S2, Y);

        gemm3_kernel<64, float><<<NNODES / 32, 256, 0, stream>>>(
            Y, W[6], W[7], W[8], W[9], W[10], W[11], Y, S1, S2);
        scatter64_kernel<<<2048, 256, 0, stream>>>(ei,  ew,  S1, Y);
        scatter64_kernel<<<2048, 256, 0, stream>>>(ei2, ew2, S2, Y);

        gemm3_out1_kernel<<<(NNODES + 255) / 256, 256, 0, stream>>>(
            Y, W[12], W[13], W[14], W[15], W[16], W[17], Y3, S1, S2);
        scatter1_kernel<<<2048, 256, 0, stream>>>(ei,  ew,  S1, Y3);
        scatter1_kernel<<<2048, 256, 0, stream>>>(ei2, ew2, S2, Y3);

        readout_kernel<<<(NNODES + 255) / 256, 256, 0, stream>>>(
            Y3, out + 4, out + 4 + NNODES, okeys);
        finalize_kernel<<<1, 64, 0, stream>>>(okeys, out);
    }
}